// Round 6
// baseline (288.804 us; speedup 1.0000x reference)
//
#include <hip/hip_runtime.h>
#include <math.h>

#ifndef M_PI
#define M_PI 3.14159265358979323846
#endif

#define Hh   256
#define Ww   1216
#define HWsz (Hh * Ww)          // 311296
#define Bb   32
#define KH   30
#define KW   49
#define NTAP (KH * KW)          // 1470
#define SHs  16
#define SWs  48
#define NPB  (SHs * SWs)        // 768 points per batch
#define NPTS (Bb * NPB)         // 24576
#define OUT0 (Bb * HWsz)        // 9961472
#define OUT1 (Bb * HWsz * 2)    // 19922944

#define CONV_BLKS (NPTS / 4)               // 6144 conv blocks, 4 waves each = 1 wave/point
#define TPOS_BLKS (Bb * (HWsz / 4) / 256)  // 9728 transpose blocks
// Interleave: 15872 total = 31 * 512. Per 31-block group: 19 transpose + 12 conv
// (exact: 512*19 = 9728, 512*12 = 6144). Keeps BW-bound streaming waves and
// latency-bound gather waves co-resident on every CU for the whole kernel,
// instead of the phase-ordered dispatch that serialized them in R5.

// Bilinear tap matching reference gather(): mask on float coords, clip-then-trunc index.
__device__ __forceinline__ float samp4(const float* __restrict__ g, float yc, float xc, float w) {
#pragma clang fp contract(off)
    bool m = (yc >= 0.0f) && (yc <= 255.0f) && (xc >= 0.0f) && (xc <= 1215.0f);
    float ycl = fminf(fmaxf(yc, 0.0f), 255.0f);
    float xcl = fminf(fmaxf(xc, 0.0f), 1215.0f);
    int yi = (int)ycl, xi = (int)xcl;
    float wm = m ? w : 0.0f;
    return g[yi * Ww + xi] * wm;
}

// One-block weight precompute: identical fp64 math to the validated in-block
// version. Runs every call (d_ws is re-poisoned each timed iteration).
__global__ __launch_bounds__(256) void k_weights(float* __restrict__ wtab) {
    __shared__ double s_gh[KH];
    __shared__ double s_gw[KW];
    __shared__ double s_invS;
    const int tid = threadIdx.x;

    if (tid < KH) {
        const double sh_ = (2.0 * 256.0 / 17.0) / 3.0;     // mirrors 2*H/(SH+1)/3.0
        double u = ((double)tid - 14.5) / sh_;             // (kh-1)/2 = 14.5
        s_gh[tid] = exp(-(u * u) / 2.0) / (sh_ * sqrt(2.0 * M_PI));
    } else if (tid >= 64 && tid < 64 + KW) {
        int t = tid - 64;
        const double sw_ = (2.0 * 1216.0 / 49.0) / 3.0;
        double u = ((double)t - 24.0) / sw_;               // (kw-1)/2 = 24.0
        s_gw[t] = exp(-(u * u) / 2.0) / (sw_ * sqrt(2.0 * M_PI));
    }
    __syncthreads();
    if (tid == 0) {
        double a = 0.0, c = 0.0;
        for (int t = 0; t < KH; ++t) a += s_gh[t];
        for (int t = 0; t < KW; ++t) c += s_gw[t];
        s_invS = 1.0 / (a * c);                            // 1/k.sum(); one fp64 divide
    }
    __syncthreads();
    const double invS = s_invS;
    for (int t = tid; t < NTAP; t += 256)
        wtab[t] = (float)((s_gh[t / KW] * s_gw[t % KW]) * invS);  // fp64->fp32 like numpy
}

// Fused kernel with interleaved block roles (see mapping above).
// Conv path: one wave per (batch,i,j) point, 23 taps/lane, fp64 FMA chain in
// exact t-ascending per-lane order (identical to all previous passing rounds).
// Transpose path: zero-fill out0 + NCHW->NHWC transpose, float4 both ways.
__global__ __launch_bounds__(256) void k_fused(
    const float* __restrict__ gt, const float* __restrict__ dvf,
    const float* __restrict__ wtab,
    float* __restrict__ out0, float* __restrict__ out1, float* __restrict__ out2,
    float* __restrict__ vbuf, int* __restrict__ rcbuf)
{
#pragma clang fp contract(off)
    const int tid = threadIdx.x;
    const int q = blockIdx.x / 31;
    const int r = blockIdx.x - q * 31;

    if (r < 19) {
        // ---- transpose + zero path ----
        const int tb = q * 19 + r;                         // [0, TPOS_BLKS)
        const size_t idx = (size_t)tb * 256 + tid;         // over Bb*HWsz/4
        ((float4*)out0)[idx] = make_float4(0.0f, 0.0f, 0.0f, 0.0f);
        const int b = (int)(idx / (HWsz / 4));
        const int rr = (int)(idx - (size_t)b * (HWsz / 4));
        const float4* p0 = (const float4*)(dvf + (size_t)b * 2 * HWsz);
        const float4* p1 = (const float4*)(dvf + (size_t)b * 2 * HWsz + HWsz);
        float4 a = p0[rr], c = p1[rr];
        float4* o = (float4*)(out1 + ((size_t)b * HWsz + (size_t)rr * 4) * 2);
        o[0] = make_float4(a.x, c.x, a.y, c.y);
        o[1] = make_float4(a.z, c.z, a.w, c.w);
        return;
    }

    // ---- conv + sample path ----
    const int cb = q * 12 + (r - 19);                      // [0, CONV_BLKS)
    const int wave = tid >> 6, lane = tid & 63;
    const int pt = cb * 4 + wave;                          // pt < NPTS exactly
    const int b = pt / NPB, p = pt - b * NPB;
    const int i = p / SWs, j = p - i * SWs;
    const int y0r = (i * 227) >> 4;                        // arange(16)*227//16
    const int x0c = (j * 1168) / 48;                       // arange(48)*1168//48
    const float* c0 = dvf + (size_t)b * (2 * HWsz) + y0r * Ww + x0c;
    const float* c1 = c0 + HWsz;

    // 22 full taps + 1 tail tap (valid for lane < 62).
    float wv[23], xa[23], xb[23];
#pragma unroll
    for (int k = 0; k < 22; ++k) {
        int t = lane + 64 * k;
        int dy = t / KW, dx = t - dy * KW;
        int off = dy * Ww + dx;
        wv[k] = wtab[t];
        xa[k] = c0[off];
        xb[k] = c1[off];
    }
    {
        int t = lane + 64 * 22;                            // 1408 + lane
        int tt = (t < NTAP) ? t : 0;                       // clamp: harmless in-bounds load
        int dy = tt / KW, dx = tt - dy * KW;
        int off = dy * Ww + dx;
        wv[22] = wtab[tt];
        xa[22] = c0[off];
        xb[22] = c1[off];
    }

    double a0 = 0.0, a1 = 0.0;
#pragma unroll
    for (int k = 0; k < 22; ++k) {
        double w = (double)wv[k];
        a0 += w * (double)xa[k];
        a1 += w * (double)xb[k];
    }
    if (lane < 62) {                                       // tail tap t=1408+lane < 1470
        double w = (double)wv[22];
        a0 += w * (double)xa[22];
        a1 += w * (double)xb[22];
    }
    for (int o = 32; o > 0; o >>= 1) {
        a0 += __shfl_down(a0, o);
        a1 += __shfl_down(a1, o);
    }

    if (lane == 0) {
        float sx = (float)a0, sy = (float)a1;              // smoothed (fp32, like ref conv out)
        // numpy linspace semantics: y = j*step + start, endpoint forced to stop.
        const double startw = -(47.0 / 48.0), stopw = 47.0 / 48.0;
        const double starth = -(15.0 / 16.0), stoph = 15.0 / 16.0;
        const double stepw = (stopw - startw) / 47.0;
        const double steph = (stoph - starth) / 15.0;
        float gwl = (j == SWs - 1) ? (float)stopw : (float)((double)j * stepw + startw);
        float ghl = (i == SHs - 1) ? (float)stoph : (float)((double)i * steph + starth);
        float gx = sx + gwl;
        float gy = sy + ghl;

        float* o2 = out2 + ((size_t)(b * SHs + i) * SWs + j) * 2;
        o2[0] = gx; o2[1] = gy;

        // bilinear: x = (gx+1)*W/2 - 0.5 with reference op order
        const float* gtb = gt + (size_t)b * HWsz;
        float xw = (gx + 1.0f) * 1216.0f; xw = xw / 2.0f; xw = xw - 0.5f;
        float yw = (gy + 1.0f) * 256.0f;  yw = yw / 2.0f; yw = yw - 0.5f;
        float x0f = floorf(xw), y0f = floorf(yw);
        float x1f = x0f + 1.0f, y1f = y0f + 1.0f;
        float wx1 = xw - x0f, wx0 = 1.0f - wx1;
        float wy1 = yw - y0f, wy0 = 1.0f - wy1;
        float v = samp4(gtb, y0f, x0f, wy0 * wx0) + samp4(gtb, y0f, x1f, wy0 * wx1)
                + samp4(gtb, y1f, x0f, wy1 * wx0) + samp4(gtb, y1f, x1f, wy1 * wx1);

        // scatter coords: trunc toward zero (astype(int32)) THEN clip
        float rf = (gy + 1.0f) / 2.0f * 256.0f;
        float cf = (gx + 1.0f) / 2.0f * 1216.0f;
        int row = (int)rf; row = row < 0 ? 0 : (row > Hh - 1 ? Hh - 1 : row);
        int col = (int)cf; col = col < 0 ? 0 : (col > Ww - 1 ? Ww - 1 : col);
        vbuf[pt]  = v;
        rcbuf[pt] = (row << 16) | col;
    }
}

// Parallel last-write-wins scatter: point p writes iff no later point p' (same batch)
// targets the same (row,col) — identical result to serial in-order replay. Rows < 96
// skipped (reference zeroes them after the scatter).
__global__ __launch_bounds__(256) void k_scatter(
    const float* __restrict__ vbuf, const int* __restrict__ rcbuf, float* __restrict__ out0)
{
    __shared__ float sv[NPB];
    __shared__ int   sr[NPB];
    const int b = blockIdx.x, tid = threadIdx.x;
    for (int t = tid; t < NPB; t += 256) {
        sv[t] = vbuf[b * NPB + t];
        sr[t] = rcbuf[b * NPB + t];
    }
    __syncthreads();
    float* o = out0 + (size_t)b * HWsz;
    for (int p = tid; p < NPB; p += 256) {
        int rc = sr[p];
        int r = rc >> 16;
        if (r < 96) continue;
        bool win = true;
        for (int q = p + 1; q < NPB; ++q) {
            if (sr[q] == rc) { win = false; break; }
        }
        if (win) o[r * Ww + (rc & 0xffff)] = sv[p];
    }
}

extern "C" void kernel_launch(void* const* d_in, const int* in_sizes, int n_in,
                              void* d_out, int out_size, void* d_ws, size_t ws_size,
                              hipStream_t stream) {
    const float* gt  = (const float*)d_in[0];
    const float* dvf = (const float*)d_in[1];
    float* out0 = (float*)d_out;
    float* out1 = out0 + OUT0;
    float* out2 = out1 + OUT1;
    float* vbuf  = (float*)d_ws;              // NPTS floats
    int*   rcbuf = (int*)d_ws + NPTS;         // NPTS ints
    float* wtab  = (float*)d_ws + 2 * NPTS;   // NTAP floats (total ~198 KiB of ws)

    hipLaunchKernelGGL(k_weights, dim3(1), dim3(256), 0, stream, wtab);
    hipLaunchKernelGGL(k_fused, dim3(CONV_BLKS + TPOS_BLKS), dim3(256), 0, stream,
                       gt, dvf, wtab, out0, out1, out2, vbuf, rcbuf);
    hipLaunchKernelGGL(k_scatter, dim3(Bb), dim3(256), 0, stream,
                       vbuf, rcbuf, out0);
}

// Round 7
// 279.940 us; speedup vs baseline: 1.0317x; 1.0317x over previous
//
#include <hip/hip_runtime.h>
#include <math.h>

#ifndef M_PI
#define M_PI 3.14159265358979323846
#endif

#define Hh   256
#define Ww   1216
#define HWsz (Hh * Ww)          // 311296
#define Bb   32
#define KH   30
#define KW   49
#define NTAP (KH * KW)          // 1470
#define SHs  16
#define SWs  48
#define NPB  (SHs * SWs)        // 768 points per batch
#define NPTS (Bb * NPB)         // 24576
#define OUT0 (Bb * HWsz)        // 9961472
#define OUT1 (Bb * HWsz * 2)    // 19922944

#define CONV_BLKS (NPTS / 4)               // 6144 conv blocks, 4 waves each = 1 wave/point
#define TPOS_BLKS (Bb * (HWsz / 4) / 256)  // 9728 transpose blocks
// Phase-ordered mapping (R5): conv blocks first, then transpose blocks.
// R6's interleave REGRESSED (84 vs 78 µs): conv is a per-wave latency chain, and
// sharing CU slots with transpose waves cut its latency hiding. Keep phases.

// Bilinear tap matching reference gather(): mask on float coords, clip-then-trunc index.
__device__ __forceinline__ float samp4(const float* __restrict__ g, float yc, float xc, float w) {
#pragma clang fp contract(off)
    bool m = (yc >= 0.0f) && (yc <= 255.0f) && (xc >= 0.0f) && (xc <= 1215.0f);
    float ycl = fminf(fmaxf(yc, 0.0f), 255.0f);
    float xcl = fminf(fmaxf(xc, 0.0f), 1215.0f);
    int yi = (int)ycl, xi = (int)xcl;
    float wm = m ? w : 0.0f;
    return g[yi * Ww + xi] * wm;
}

// One-block weight precompute: identical fp64 math to the validated in-block
// version. Runs every call (d_ws is re-poisoned each timed iteration).
__global__ __launch_bounds__(256) void k_weights(float* __restrict__ wtab) {
    __shared__ double s_gh[KH];
    __shared__ double s_gw[KW];
    __shared__ double s_invS;
    const int tid = threadIdx.x;

    if (tid < KH) {
        const double sh_ = (2.0 * 256.0 / 17.0) / 3.0;     // mirrors 2*H/(SH+1)/3.0
        double u = ((double)tid - 14.5) / sh_;             // (kh-1)/2 = 14.5
        s_gh[tid] = exp(-(u * u) / 2.0) / (sh_ * sqrt(2.0 * M_PI));
    } else if (tid >= 64 && tid < 64 + KW) {
        int t = tid - 64;
        const double sw_ = (2.0 * 1216.0 / 49.0) / 3.0;
        double u = ((double)t - 24.0) / sw_;               // (kw-1)/2 = 24.0
        s_gw[t] = exp(-(u * u) / 2.0) / (sw_ * sqrt(2.0 * M_PI));
    }
    __syncthreads();
    if (tid == 0) {
        double a = 0.0, c = 0.0;
        for (int t = 0; t < KH; ++t) a += s_gh[t];
        for (int t = 0; t < KW; ++t) c += s_gw[t];
        s_invS = 1.0 / (a * c);                            // 1/k.sum(); one fp64 divide
    }
    __syncthreads();
    const double invS = s_invS;
    for (int t = tid; t < NTAP; t += 256)
        wtab[t] = (float)((s_gh[t / KW] * s_gw[t % KW]) * invS);  // fp64->fp32 like numpy
}

// Fused kernel, phase-ordered. Conv path: one wave per point; ALL 69 operands
// (23 w + 23 xa + 23 xb) force-preloaded into registers via an asm fence so the
// 69 global loads pipeline as one batch (one latency exposure) instead of the
// compiler's load-next-to-use schedule (23 serial exposures — the R5/R6 stall).
// FMA chain order unchanged (t-ascending per lane) -> bit-identical result.
__global__ __launch_bounds__(256) void k_fused(
    const float* __restrict__ gt, const float* __restrict__ dvf,
    const float* __restrict__ wtab,
    float* __restrict__ out0, float* __restrict__ out1, float* __restrict__ out2,
    float* __restrict__ vbuf, int* __restrict__ rcbuf)
{
#pragma clang fp contract(off)
    const int tid = threadIdx.x;

    if (blockIdx.x >= CONV_BLKS) {
        // ---- transpose + zero path ----
        const size_t idx = (size_t)(blockIdx.x - CONV_BLKS) * 256 + tid;  // over Bb*HWsz/4
        ((float4*)out0)[idx] = make_float4(0.0f, 0.0f, 0.0f, 0.0f);
        const int b = (int)(idx / (HWsz / 4));
        const int rr = (int)(idx - (size_t)b * (HWsz / 4));
        const float4* p0 = (const float4*)(dvf + (size_t)b * 2 * HWsz);
        const float4* p1 = (const float4*)(dvf + (size_t)b * 2 * HWsz + HWsz);
        float4 a = p0[rr], c = p1[rr];
        float4* o = (float4*)(out1 + ((size_t)b * HWsz + (size_t)rr * 4) * 2);
        o[0] = make_float4(a.x, c.x, a.y, c.y);
        o[1] = make_float4(a.z, c.z, a.w, c.w);
        return;
    }

    // ---- conv + sample path ----
    const int wave = tid >> 6, lane = tid & 63;
    const int pt = blockIdx.x * 4 + wave;                  // pt < NPTS exactly
    const int b = pt / NPB, p = pt - b * NPB;
    const int i = p / SWs, j = p - i * SWs;
    const int y0r = (i * 227) >> 4;                        // arange(16)*227//16
    const int x0c = (j * 1168) / 48;                       // arange(48)*1168//48
    const float* c0 = dvf + (size_t)b * (2 * HWsz) + y0r * Ww + x0c;
    const float* c1 = c0 + HWsz;

    // Preload 22 full taps + 1 tail tap (valid for lane < 62) into registers.
    float wv[23], xa[23], xb[23];
#pragma unroll
    for (int k = 0; k < 22; ++k) {
        int t = lane + 64 * k;
        int dy = t / KW, dx = t - dy * KW;
        int off = dy * Ww + dx;
        wv[k] = wtab[t];
        xa[k] = c0[off];
        xb[k] = c1[off];
    }
    {
        int t = lane + 64 * 22;                            // 1408 + lane
        int tt = (t < NTAP) ? t : 0;                       // clamp: harmless in-bounds load
        int dy = tt / KW, dx = tt - dy * KW;
        int off = dy * Ww + dx;
        wv[22] = wtab[tt];
        xa[22] = c0[off];
        xb[22] = c1[off];
    }
    // Force all 69 loads to be issued/materialized BEFORE the FMA chain:
    // one batched latency exposure instead of 23 serial ones.
#pragma unroll
    for (int k = 0; k < 23; ++k)
        asm volatile("" :: "v"(wv[k]), "v"(xa[k]), "v"(xb[k]));

    double a0 = 0.0, a1 = 0.0;
#pragma unroll
    for (int k = 0; k < 22; ++k) {
        double w = (double)wv[k];
        a0 += w * (double)xa[k];
        a1 += w * (double)xb[k];
    }
    if (lane < 62) {                                       // tail tap t=1408+lane < 1470
        double w = (double)wv[22];
        a0 += w * (double)xa[22];
        a1 += w * (double)xb[22];
    }
    for (int o = 32; o > 0; o >>= 1) {
        a0 += __shfl_down(a0, o);
        a1 += __shfl_down(a1, o);
    }

    if (lane == 0) {
        float sx = (float)a0, sy = (float)a1;              // smoothed (fp32, like ref conv out)
        // numpy linspace semantics: y = j*step + start, endpoint forced to stop.
        const double startw = -(47.0 / 48.0), stopw = 47.0 / 48.0;
        const double starth = -(15.0 / 16.0), stoph = 15.0 / 16.0;
        const double stepw = (stopw - startw) / 47.0;
        const double steph = (stoph - starth) / 15.0;
        float gwl = (j == SWs - 1) ? (float)stopw : (float)((double)j * stepw + startw);
        float ghl = (i == SHs - 1) ? (float)stoph : (float)((double)i * steph + starth);
        float gx = sx + gwl;
        float gy = sy + ghl;

        float* o2 = out2 + ((size_t)(b * SHs + i) * SWs + j) * 2;
        o2[0] = gx; o2[1] = gy;

        // bilinear: x = (gx+1)*W/2 - 0.5 with reference op order
        const float* gtb = gt + (size_t)b * HWsz;
        float xw = (gx + 1.0f) * 1216.0f; xw = xw / 2.0f; xw = xw - 0.5f;
        float yw = (gy + 1.0f) * 256.0f;  yw = yw / 2.0f; yw = yw - 0.5f;
        float x0f = floorf(xw), y0f = floorf(yw);
        float x1f = x0f + 1.0f, y1f = y0f + 1.0f;
        float wx1 = xw - x0f, wx0 = 1.0f - wx1;
        float wy1 = yw - y0f, wy0 = 1.0f - wy1;
        float v = samp4(gtb, y0f, x0f, wy0 * wx0) + samp4(gtb, y0f, x1f, wy0 * wx1)
                + samp4(gtb, y1f, x0f, wy1 * wx0) + samp4(gtb, y1f, x1f, wy1 * wx1);

        // scatter coords: trunc toward zero (astype(int32)) THEN clip
        float rf = (gy + 1.0f) / 2.0f * 256.0f;
        float cf = (gx + 1.0f) / 2.0f * 1216.0f;
        int row = (int)rf; row = row < 0 ? 0 : (row > Hh - 1 ? Hh - 1 : row);
        int col = (int)cf; col = col < 0 ? 0 : (col > Ww - 1 ? Ww - 1 : col);
        vbuf[pt]  = v;
        rcbuf[pt] = (row << 16) | col;
    }
}

// Parallel last-write-wins scatter: point p writes iff no later point p' (same batch)
// targets the same (row,col) — identical result to serial in-order replay. Rows < 96
// skipped (reference zeroes them after the scatter).
__global__ __launch_bounds__(256) void k_scatter(
    const float* __restrict__ vbuf, const int* __restrict__ rcbuf, float* __restrict__ out0)
{
    __shared__ float sv[NPB];
    __shared__ int   sr[NPB];
    const int b = blockIdx.x, tid = threadIdx.x;
    for (int t = tid; t < NPB; t += 256) {
        sv[t] = vbuf[b * NPB + t];
        sr[t] = rcbuf[b * NPB + t];
    }
    __syncthreads();
    float* o = out0 + (size_t)b * HWsz;
    for (int p = tid; p < NPB; p += 256) {
        int rc = sr[p];
        int r = rc >> 16;
        if (r < 96) continue;
        bool win = true;
        for (int q = p + 1; q < NPB; ++q) {
            if (sr[q] == rc) { win = false; break; }
        }
        if (win) o[r * Ww + (rc & 0xffff)] = sv[p];
    }
}

extern "C" void kernel_launch(void* const* d_in, const int* in_sizes, int n_in,
                              void* d_out, int out_size, void* d_ws, size_t ws_size,
                              hipStream_t stream) {
    const float* gt  = (const float*)d_in[0];
    const float* dvf = (const float*)d_in[1];
    float* out0 = (float*)d_out;
    float* out1 = out0 + OUT0;
    float* out2 = out1 + OUT1;
    float* vbuf  = (float*)d_ws;              // NPTS floats
    int*   rcbuf = (int*)d_ws + NPTS;         // NPTS ints
    float* wtab  = (float*)d_ws + 2 * NPTS;   // NTAP floats (total ~198 KiB of ws)

    hipLaunchKernelGGL(k_weights, dim3(1), dim3(256), 0, stream, wtab);
    hipLaunchKernelGGL(k_fused, dim3(CONV_BLKS + TPOS_BLKS), dim3(256), 0, stream,
                       gt, dvf, wtab, out0, out1, out2, vbuf, rcbuf);
    hipLaunchKernelGGL(k_scatter, dim3(Bb), dim3(256), 0, stream,
                       vbuf, rcbuf, out0);
}